// Round 6
// baseline (485.629 us; speedup 1.0000x reference)
//
#include <hip/hip_runtime.h>

// Problem: SphereConv2DEXP — grid_sample(bilinear) + 3x3/stride-3 conv
//   == implicit GEMM: M=131072, N=256, K=1152.
//
// R6 (= R5 resubmit after infra failure, lambda flattened):
// B never touches LDS. The mfma B-fragment is a contiguous coalesced 1KB
// wave read from wt2[ks][n][kk] (lane addr = (n=wcol*64+c*16+l16)*32 + quad*8
// f16) -> load straight from global (L2-resident, 576 KB), double-register-
// buffered (bc/bn) with the K-loop unrolled x2 for static indexing.
// LDS per block-step drops 68 -> 20 wave-b128 ops; LDS size 65KB -> 24KB.
// A stays LDS-staged (gather dedup), R4 pipeline kept: issue next-step gather
// at iter top, MFMA current, interp+ds_write, one barrier per step.
// Prep transpose: float4 reads, 4 sp x 8 ch per thread.

#define Hh   128
#define Ww   256
#define HWp  (Hh*Ww)        // 32768 per-channel image size
#define CIN  128
#define COUT 256
#define KTOT 1152
#define NPTS (384*768)      // 294912 grid points
#define BM   64
#define BN   256
#define BK   32
#define NKS  (KTOT/BK)      // 36 K-steps

typedef __attribute__((ext_vector_type(8))) _Float16 f16x8;
typedef __attribute__((ext_vector_type(4))) float    f32x4;

__device__ __forceinline__ f16x8 bcast8(float f) {
    _Float16 h = (_Float16)f;
    f16x8 v;
#pragma unroll
    for (int i = 0; i < 8; ++i) v[i] = h;
    return v;
}

// ---------------------------------------------------------------------------
// Prep kernel: blocks [0,1152) bilinear tap table; [1152,2304) weights -> f16
// retiled wt2[ks][n][kk] (K order: ks -> ij = ks%9, ci = (ks/9)*32 + kk);
// [2304,4352) x NCHW -> NHWC f16 transpose (4 sp x 8 ch per thread).
// ---------------------------------------------------------------------------
__global__ void prep(const float* __restrict__ grid, const float* __restrict__ w,
                     const float* __restrict__ x,
                     int2* __restrict__ tI, float4* __restrict__ tW,
                     _Float16* __restrict__ wt2, _Float16* __restrict__ xt) {
    const int bid = blockIdx.x;
    const int t   = threadIdx.x;
    if (bid < NPTS / 256) {
        int g = bid * 256 + t;
        int hh = g / 768, ww = g - hh * 768;
        int ho = hh / 3, ii = hh - 3 * ho;
        int wo = ww / 3, jj = ww - 3 * wo;

        float gx = grid[2 * g + 0];
        float gy = grid[2 * g + 1];
        float ix = ((gx + 1.0f) * (float)Ww - 1.0f) * 0.5f;
        float iy = ((gy + 1.0f) * (float)Hh - 1.0f) * 0.5f;
        float x0f = floorf(ix), y0f = floorf(iy);
        int x0 = (int)x0f, y0 = (int)y0f;
        float wx1 = ix - x0f, wx0 = 1.0f - wx1;
        float wy1 = iy - y0f, wy0 = 1.0f - wy1;

        float wyt = (y0 >= 0 && y0 < Hh) ? wy0 : 0.0f;
        float wyb = (y0 + 1 >= 0 && y0 + 1 < Hh) ? wy1 : 0.0f;
        int r0 = min(max(y0, 0), Hh - 1);
        int r1 = min(max(y0 + 1, 0), Hh - 1);

        int xb; float cw0, cw1;
        if (x0 < 0)            { xb = 0;      cw0 = wx1; cw1 = 0.0f; }
        else if (x0 > Ww - 2)  { xb = Ww - 2; cw0 = 0.0f; cw1 = wx0; }
        else                   { xb = x0;     cw0 = wx0; cw1 = wx1; }

        int e = (ho * Ww + wo) * 9 + ii * 3 + jj;   // (sp, ij) order
        tI[e] = make_int2(r0 * Ww + xb, r1 * Ww + xb);
        tW[e] = make_float4(cw0 * wyt, cw1 * wyt, cw0 * wyb, cw1 * wyb);
    } else if (bid < 2 * (NPTS / 256)) {
        int o = (bid - NPTS / 256) * 256 + t;       // NKS*COUT*BK = 294912
        int kk = o & (BK - 1);
        int n  = (o >> 5) & (COUT - 1);
        int ks = o >> 13;
        int ij = ks % 9;
        int ci = (ks / 9) * 32 + kk;
        wt2[o] = (_Float16)w[n * KTOT + ci * 9 + ij];
    } else {
        // transpose: thread handles 4 consecutive sp x 8 channels
        int r   = (bid - 2 * (NPTS / 256)) * 256 + t;   // 0 .. 524287
        int sp4 = (r & 8191) * 4;
        int cg  = (r >> 13) & 15;
        int b   = r >> 17;
        const float* src = x + ((size_t)(b * CIN + cg * 8)) * HWp + sp4;
        float4 v[8];
#pragma unroll
        for (int j = 0; j < 8; ++j) v[j] = *(const float4*)(src + (size_t)j * HWp);
#pragma unroll
        for (int s = 0; s < 4; ++s) {
            f16x8 ov;
#pragma unroll
            for (int j = 0; j < 8; ++j) ov[j] = (_Float16)((&v[j].x)[s]);
            *(f16x8*)&xt[((size_t)(b * HWp + sp4 + s)) * CIN + cg * 8] = ov;
        }
    }
}

// ---------------------------------------------------------------------------
// Fused gather + f16 MFMA GEMM.  Block: 512 thr (8 waves, 2x4), tile 64x256,
// K-step 32 channels, step ks: ij = ks%9, channels (ks/9)*32 .. +31.
// Waves 0-3 gather/stage A into LDS; B fragments come straight from global,
// register-double-buffered, K-loop unrolled x2 (static reg indexing).
// One __syncthreads per step (A staging only).
// ---------------------------------------------------------------------------
__global__ __launch_bounds__(512, 4) void sphconv_gemm(
    const _Float16* __restrict__ xt, const _Float16* __restrict__ wt2,
    const float* __restrict__ bias, const int2* __restrict__ tI,
    const float4* __restrict__ tW, float* __restrict__ out) {

    __shared__ int2   sTI[9 * BM];                       //  4608 B  [ij][sp]
    __shared__ float4 sTW[9 * BM];                       //  9216 B  [ij][sp]
    __shared__ __align__(16) _Float16 sA[2][BM * 40];    // 2x 5120 B -> 24064 total

    const int t = threadIdx.x;
    // chunked XCD swizzle: 2048 blocks, 8 XCDs, bijective (2048 % 8 == 0)
    const int bid = blockIdx.x;
    const int swz = (bid & 7) * 256 + (bid >> 3);
    const int m0  = swz * BM;
    const int b   = m0 >> 15;           // / 32768
    const int sp0 = m0 & (HWp - 1);
    const _Float16* xb_ = xt + (size_t)b * (HWp * CIN);

    // tap table, [ij][sp] so in-loop lane reads are contiguous
    for (int e = t; e < 9 * BM; e += 512) {
        int r = e & (BM - 1), ij = e >> 6;
        sTI[e] = tI[(sp0 + r) * 9 + ij];
        sTW[e] = tW[(sp0 + r) * 9 + ij];
    }

    const int lane = t & 63;
    const int wid  = t >> 6;
    const int wrow = wid >> 2;          // 0..1 -> m offset 32*wrow
    const int wcol = wid & 3;           // 0..3 -> n offset 64*wcol
    const int quad = lane >> 4;         // 0..3
    const int l16  = lane & 15;

    const bool isA = (t < 256);
    const int  mr  = t & 63;            // A staging row
    const int  chb = ((t >> 6) & 3) * 8;// A channel sub-base (0,8,16,24)

    // per-wave global base for B fragments: lane offset (n*32 + quad*8) f16
    const _Float16* wfrag = wt2 + (wcol * 64 + l16) * BK + quad * 8;

    f32x4 acc[2][4];
#pragma unroll
    for (int r = 0; r < 2; ++r)
#pragma unroll
        for (int c = 0; c < 4; ++c) {
            f32x4 z = {0.0f, 0.0f, 0.0f, 0.0f};
            acc[r][c] = z;
        }

    __syncthreads();  // table ready

    // ---- prologue: stage A step 0, load B frags step 0 ----
    f16x8 bc[4], bn[4];
    if (isA) {
        const int2   o  = sTI[mr];      // ij=0
        const float4 wv = sTW[mr];
        const _Float16* p = xb_ + (size_t)o.x * CIN + chb;
        const _Float16* q = xb_ + (size_t)o.y * CIN + chb;
        f16x8 av = (*(const f16x8*)p)         * bcast8(wv.x)
                 + (*(const f16x8*)(p + CIN)) * bcast8(wv.y)
                 + (*(const f16x8*)q)         * bcast8(wv.z)
                 + (*(const f16x8*)(q + CIN)) * bcast8(wv.w);
        *(f16x8*)&sA[0][mr * 40 + chb] = av;
    }
#pragma unroll
    for (int c = 0; c < 4; ++c)
        bc[c] = *(const f16x8*)(wfrag + c * 16 * BK);
    __syncthreads();  // sA[0] ready

#define STEP_BODY(KS, CURA, NXTA, BCUR, BNXT)                                   \
    {                                                                           \
        const int  ks_   = (KS);                                                \
        const bool have_ = (ks_ + 1 < NKS);                                     \
        f16x8 p00, p01, p10, p11;                                               \
        float4 wv;                                                              \
        if (isA && have_) {                                                     \
            const int ij2 = (ks_ + 1) % 9;                                      \
            const int cb2 = ((ks_ + 1) / 9) * 32;                               \
            const int2 o = sTI[ij2 * BM + mr];                                  \
            wv = sTW[ij2 * BM + mr];                                            \
            const _Float16* p = xb_ + (size_t)o.x * CIN + cb2 + chb;            \
            const _Float16* q = xb_ + (size_t)o.y * CIN + cb2 + chb;            \
            p00 = *(const f16x8*)p;  p01 = *(const f16x8*)(p + CIN);            \
            p10 = *(const f16x8*)q;  p11 = *(const f16x8*)(q + CIN);            \
        }                                                                       \
        if (have_) {                                                            \
            const _Float16* src = wfrag + (size_t)(ks_ + 1) * (COUT * BK);      \
            _Pragma("unroll")                                                   \
            for (int c = 0; c < 4; ++c)                                         \
                BNXT[c] = *(const f16x8*)(src + c * 16 * BK);                   \
        }                                                                       \
        f16x8 af[2];                                                            \
        _Pragma("unroll")                                                       \
        for (int r = 0; r < 2; ++r)                                             \
            af[r] = *(const f16x8*)(&CURA[(wrow * 32 + r * 16 + l16) * 40 +     \
                                          quad * 8]);                           \
        _Pragma("unroll")                                                       \
        for (int r = 0; r < 2; ++r)                                             \
            _Pragma("unroll")                                                   \
            for (int c = 0; c < 4; ++c)                                         \
                acc[r][c] = __builtin_amdgcn_mfma_f32_16x16x32_f16(             \
                    af[r], BCUR[c], acc[r][c], 0, 0, 0);                        \
        if (isA && have_) {                                                     \
            f16x8 av = p00 * bcast8(wv.x) + p01 * bcast8(wv.y)                  \
                     + p10 * bcast8(wv.z) + p11 * bcast8(wv.w);                 \
            *(f16x8*)&NXTA[mr * 40 + chb] = av;                                 \
        }                                                                       \
        __syncthreads();                                                        \
    }

    for (int ks = 0; ks < NKS; ks += 2) {
        STEP_BODY(ks,     sA[0], sA[1], bc, bn)
        STEP_BODY(ks + 1, sA[1], sA[0], bn, bc)
    }
#undef STEP_BODY

    // ---- epilogue: D row=(quad*4+i), col=(lane&15)  [m89-verified layout] ----
#pragma unroll
    for (int c = 0; c < 4; ++c) {
        int n = wcol * 64 + c * 16 + l16;
        float bv = bias[n];
        float* outn = out + (((size_t)(b * COUT + n)) << 15) + sp0;
#pragma unroll
        for (int r = 0; r < 2; ++r) {
            int mbase = wrow * 32 + r * 16 + quad * 4;
            float4 v = make_float4(acc[r][c][0] + bv, acc[r][c][1] + bv,
                                   acc[r][c][2] + bv, acc[r][c][3] + bv);
            *(float4*)(&outn[mbase]) = v;   // 16B aligned
        }
    }
}

// ---------------------------------------------------------------------------
extern "C" void kernel_launch(void* const* d_in, const int* in_sizes, int n_in,
                              void* d_out, int out_size, void* d_ws, size_t ws_size,
                              hipStream_t stream) {
    const float* x    = (const float*)d_in[0];
    const float* w    = (const float*)d_in[1];
    const float* bias = (const float*)d_in[2];
    const float* grid = (const float*)d_in[3];
    float* out = (float*)d_out;

    char* ws = (char*)d_ws;
    int2*     tI  = (int2*)(ws);                    // 294912*8  = 2359296 B
    float4*   tW  = (float4*)(ws + 2359296);        // 294912*16 = 4718592 B
    _Float16* wt2 = (_Float16*)(ws + 7077888);      // 294912*2  =  589824 B
    _Float16* xt  = (_Float16*)(ws + 7667712);      // 16.7M*2   = 33554432 B
                                                    // total 41222144 B

    prep<<<1152 + 1152 + 2048, 256, 0, stream>>>(grid, w, x, tI, tW, wt2, xt);
    sphconv_gemm<<<(4 * HWp) / BM, 512, 0, stream>>>(xt, wt2, bias, tI, tW, out);
}

// Round 8
// 446.946 us; speedup vs baseline: 1.0865x; 1.0865x over previous
//
#include <hip/hip_runtime.h>

// Problem: SphereConv2DEXP — grid_sample(bilinear) + 3x3/stride-3 conv
//   == implicit GEMM: M=131072, N=256, K=1152.
//
// R8 (= R7 resubmit after infra failure; audited for hang/OOB — none):
//  (a) raw s_barrier + lgkmcnt(0)-only (+sched_barrier) -> B/gather prefetch
//      survives the barrier; compiler emits counted vmcnt (T4), no drain.
//  (b) BK=64 superstep: 18 barriers instead of 36; A-gather symmetric across
//      all 512 threads (group t>>8 stages one of the two ij-halves).
//  (c) wave tile 64x32 (wcol=wid): zero B-fragment duplication -> B VMEM
//      halves; acc[4][2]=32 AGPR keeps combined regs <=128 -> 2 blocks/CU.

#define Hh   128
#define Ww   256
#define HWp  (Hh*Ww)        // 32768 per-channel image size
#define CIN  128
#define COUT 256
#define KTOT 1152
#define NPTS (384*768)      // 294912 grid points
#define BM   64
#define BN   256
#define BK   32
#define NKS  (KTOT/BK)      // 36 K-steps
#define NSS  (NKS/2)        // 18 supersteps (BK=64 each)

typedef __attribute__((ext_vector_type(8))) _Float16 f16x8;
typedef __attribute__((ext_vector_type(4))) float    f32x4;

__device__ __forceinline__ f16x8 bcast8(float f) {
    _Float16 h = (_Float16)f;
    f16x8 v;
#pragma unroll
    for (int i = 0; i < 8; ++i) v[i] = h;
    return v;
}

// ---------------------------------------------------------------------------
// Prep kernel (unchanged, verified): blocks [0,1152) tap table;
// [1152,2304) weights -> f16 retiled wt2[ks][n][kk] (ks -> ij=ks%9,
// ci=(ks/9)*32+kk); [2304,4352) x NCHW -> NHWC f16 transpose.
// ---------------------------------------------------------------------------
__global__ void prep(const float* __restrict__ grid, const float* __restrict__ w,
                     const float* __restrict__ x,
                     int2* __restrict__ tI, float4* __restrict__ tW,
                     _Float16* __restrict__ wt2, _Float16* __restrict__ xt) {
    const int bid = blockIdx.x;
    const int t   = threadIdx.x;
    if (bid < NPTS / 256) {
        int g = bid * 256 + t;
        int hh = g / 768, ww = g - hh * 768;
        int ho = hh / 3, ii = hh - 3 * ho;
        int wo = ww / 3, jj = ww - 3 * wo;

        float gx = grid[2 * g + 0];
        float gy = grid[2 * g + 1];
        float ix = ((gx + 1.0f) * (float)Ww - 1.0f) * 0.5f;
        float iy = ((gy + 1.0f) * (float)Hh - 1.0f) * 0.5f;
        float x0f = floorf(ix), y0f = floorf(iy);
        int x0 = (int)x0f, y0 = (int)y0f;
        float wx1 = ix - x0f, wx0 = 1.0f - wx1;
        float wy1 = iy - y0f, wy0 = 1.0f - wy1;

        float wyt = (y0 >= 0 && y0 < Hh) ? wy0 : 0.0f;
        float wyb = (y0 + 1 >= 0 && y0 + 1 < Hh) ? wy1 : 0.0f;
        int r0 = min(max(y0, 0), Hh - 1);
        int r1 = min(max(y0 + 1, 0), Hh - 1);

        int xb; float cw0, cw1;
        if (x0 < 0)            { xb = 0;      cw0 = wx1; cw1 = 0.0f; }
        else if (x0 > Ww - 2)  { xb = Ww - 2; cw0 = 0.0f; cw1 = wx0; }
        else                   { xb = x0;     cw0 = wx0; cw1 = wx1; }

        int e = (ho * Ww + wo) * 9 + ii * 3 + jj;   // (sp, ij) order
        tI[e] = make_int2(r0 * Ww + xb, r1 * Ww + xb);
        tW[e] = make_float4(cw0 * wyt, cw1 * wyt, cw0 * wyb, cw1 * wyb);
    } else if (bid < 2 * (NPTS / 256)) {
        int o = (bid - NPTS / 256) * 256 + t;       // NKS*COUT*BK = 294912
        int kk = o & (BK - 1);
        int n  = (o >> 5) & (COUT - 1);
        int ks = o >> 13;
        int ij = ks % 9;
        int ci = (ks / 9) * 32 + kk;
        wt2[o] = (_Float16)w[n * KTOT + ci * 9 + ij];
    } else {
        // transpose: thread handles 4 consecutive sp x 8 channels
        int r   = (bid - 2 * (NPTS / 256)) * 256 + t;   // 0 .. 524287
        int sp4 = (r & 8191) * 4;
        int cg  = (r >> 13) & 15;
        int b   = r >> 17;
        const float* src = x + ((size_t)(b * CIN + cg * 8)) * HWp + sp4;
        float4 v[8];
#pragma unroll
        for (int j = 0; j < 8; ++j) v[j] = *(const float4*)(src + (size_t)j * HWp);
#pragma unroll
        for (int s = 0; s < 4; ++s) {
            f16x8 ov;
#pragma unroll
            for (int j = 0; j < 8; ++j) ov[j] = (_Float16)((&v[j].x)[s]);
            *(f16x8*)&xt[((size_t)(b * HWp + sp4 + s)) * CIN + cg * 8] = ov;
        }
    }
}

// ---------------------------------------------------------------------------
// Fused gather + f16 MFMA GEMM.  Block: 512 thr (8 waves), tile 64x256,
// superstep = 64 k (two BK=32 steps: ks0=2S (k 0..31), ks1=2S+1 (k 32..63)).
// Wave w owns cols [w*32, w*32+32): acc[4][2], af[4] per k-half, B frags from
// GLOBAL (no duplication), double-register-buffered across the raw barrier.
// A staged in LDS sA[2][64][72]; all 512 threads gather (group g = t>>8
// handles ij of step 2S+g: 4x16B channel-contiguous loads + packed interp).
// One raw s_barrier per superstep; vmcnt never drained in the loop.
// ---------------------------------------------------------------------------
__global__ __launch_bounds__(512, 4) void sphconv_gemm(
    const _Float16* __restrict__ xt, const _Float16* __restrict__ wt2,
    const float* __restrict__ bias, const int2* __restrict__ tI,
    const float4* __restrict__ tW, float* __restrict__ out) {

    __shared__ int2   sTI[9 * BM];                       //  4608 B  [ij][sp]
    __shared__ float4 sTW[9 * BM];                       //  9216 B  [ij][sp]
    __shared__ __align__(16) _Float16 sA[2][BM * 72];    // 2x 9216 B -> 32256 total

    const int t = threadIdx.x;
    // chunked XCD swizzle: 2048 blocks, 8 XCDs, bijective (2048 % 8 == 0)
    const int bid = blockIdx.x;
    const int swz = (bid & 7) * 256 + (bid >> 3);
    const int m0  = swz * BM;
    const int b   = m0 >> 15;           // / 32768
    const int sp0 = m0 & (HWp - 1);
    const _Float16* xb_ = xt + (size_t)b * (HWp * CIN);

    // tap table, [ij][sp] so in-loop lane reads are contiguous
    for (int e = t; e < 9 * BM; e += 512) {
        int r = e & (BM - 1), ij = e >> 6;
        sTI[e] = tI[(sp0 + r) * 9 + ij];
        sTW[e] = tW[(sp0 + r) * 9 + ij];
    }

    const int lane = t & 63;
    const int wid  = t >> 6;
    const int wcol = wid;               // 0..7 -> n offset 32*wcol
    const int quad = lane >> 4;         // 0..3
    const int l16  = lane & 15;
    const int qk   = quad * 8;

    const int row = t & 63;             // A staging row (fixed sp per thread)
    const int chb = ((t >> 6) & 3) * 8; // channel sub-base 0/8/16/24
    const int g   = t >> 8;             // 0/1 -> stages step 2S+g (k-half g)

    // per-lane global base for B fragments: (n = wcol*32 + l16) * 32 + quad*8
    const int wb = (wcol * 32 + l16) * BK + qk;

    f32x4 acc[4][2];
#pragma unroll
    for (int r = 0; r < 4; ++r)
#pragma unroll
        for (int c = 0; c < 2; ++c) {
            f32x4 z = {0.0f, 0.0f, 0.0f, 0.0f};
            acc[r][c] = z;
        }

    __syncthreads();  // table ready

    // ---- prologue: stage superstep 0 (A into sA[0], B regs bcA) ----
    f16x8 bcA[4], bcB[4];
    {
        const int2   o  = sTI[g * BM + row];     // ij = g (ks = g, cb = 0)
        const float4 wv = sTW[g * BM + row];
        const _Float16* p = xb_ + (size_t)o.x * CIN + chb;
        const _Float16* q = xb_ + (size_t)o.y * CIN + chb;
        f16x8 av = (*(const f16x8*)p)         * bcast8(wv.x)
                 + (*(const f16x8*)(p + CIN)) * bcast8(wv.y)
                 + (*(const f16x8*)q)         * bcast8(wv.z)
                 + (*(const f16x8*)(q + CIN)) * bcast8(wv.w);
        *(f16x8*)&sA[0][row * 72 + g * 32 + chb] = av;
        const _Float16* ws0 = wt2 + wb;          // superstep 0: ks0=0, ks1=1
        bcA[0] = *(const f16x8*)(ws0);
        bcA[1] = *(const f16x8*)(ws0 + 16 * BK);
        bcA[2] = *(const f16x8*)(ws0 + COUT * BK);
        bcA[3] = *(const f16x8*)(ws0 + COUT * BK + 16 * BK);
    }
    __syncthreads();  // sA[0] ready (prologue drain is harmless)

#define SUPER(S, CUR, NXT, BC, BN)                                              \
    {                                                                           \
        const bool have_ = ((S) + 1 < NSS);                                     \
        f16x8 p00, p01, p10, p11;                                               \
        float4 wvn;                                                             \
        if (have_) {                                                            \
            const int mk  = 2 * ((S) + 1) + g;                                  \
            const int ijn = mk % 9;                                             \
            const int cbn = (mk / 9) * 32;                                      \
            const int2 o  = sTI[ijn * BM + row];                                \
            wvn = sTW[ijn * BM + row];                                          \
            const _Float16* p = xb_ + (size_t)o.x * CIN + cbn + chb;            \
            const _Float16* q = xb_ + (size_t)o.y * CIN + cbn + chb;            \
            p00 = *(const f16x8*)p;  p01 = *(const f16x8*)(p + CIN);            \
            p10 = *(const f16x8*)q;  p11 = *(const f16x8*)(q + CIN);            \
            const _Float16* ws_ = wt2 + (size_t)(2 * ((S) + 1)) * (COUT * BK)   \
                                      + wb;                                     \
            BN[0] = *(const f16x8*)(ws_);                                       \
            BN[1] = *(const f16x8*)(ws_ + 16 * BK);                             \
            BN[2] = *(const f16x8*)(ws_ + COUT * BK);                           \
            BN[3] = *(const f16x8*)(ws_ + COUT * BK + 16 * BK);                 \
        }                                                                       \
        _Pragma("unroll")                                                       \
        for (int kh = 0; kh < 2; ++kh) {                                        \
            f16x8 af[4];                                                        \
            _Pragma("unroll")                                                   \
            for (int r = 0; r < 4; ++r)                                         \
                af[r] = *(const f16x8*)(&CUR[(r * 16 + l16) * 72 +              \
                                             kh * 32 + qk]);                    \
            _Pragma("unroll")                                                   \
            for (int r = 0; r < 4; ++r)                                         \
                _Pragma("unroll")                                               \
                for (int c = 0; c < 2; ++c)                                     \
                    acc[r][c] = __builtin_amdgcn_mfma_f32_16x16x32_f16(         \
                        af[r], BC[kh * 2 + c], acc[r][c], 0, 0, 0);             \
        }                                                                       \
        if (have_) {                                                            \
            f16x8 av = p00 * bcast8(wvn.x) + p01 * bcast8(wvn.y)                \
                     + p10 * bcast8(wvn.z) + p11 * bcast8(wvn.w);               \
            *(f16x8*)&NXT[row * 72 + g * 32 + chb] = av;                        \
        }                                                                       \
        asm volatile("s_waitcnt lgkmcnt(0)" ::: "memory");                      \
        __builtin_amdgcn_s_barrier();                                           \
        __builtin_amdgcn_sched_barrier(0);                                      \
    }

    for (int s = 0; s < NSS; s += 2) {
        SUPER(s,     sA[0], sA[1], bcA, bcB)
        SUPER(s + 1, sA[1], sA[0], bcB, bcA)
    }
#undef SUPER

    // ---- epilogue: D row=(quad*4+i), col=(lane&15)  [m89-verified layout] ----
#pragma unroll
    for (int c = 0; c < 2; ++c) {
        int n = wcol * 32 + c * 16 + l16;
        float bv = bias[n];
        float* outn = out + (((size_t)(b * COUT + n)) << 15) + sp0;
#pragma unroll
        for (int r = 0; r < 4; ++r) {
            int mbase = r * 16 + quad * 4;
            float4 v = make_float4(acc[r][c][0] + bv, acc[r][c][1] + bv,
                                   acc[r][c][2] + bv, acc[r][c][3] + bv);
            *(float4*)(&outn[mbase]) = v;   // 16B aligned
        }
    }
}

// ---------------------------------------------------------------------------
extern "C" void kernel_launch(void* const* d_in, const int* in_sizes, int n_in,
                              void* d_out, int out_size, void* d_ws, size_t ws_size,
                              hipStream_t stream) {
    const float* x    = (const float*)d_in[0];
    const float* w    = (const float*)d_in[1];
    const float* bias = (const float*)d_in[2];
    const float* grid = (const float*)d_in[3];
    float* out = (float*)d_out;

    char* ws = (char*)d_ws;
    int2*     tI  = (int2*)(ws);                    // 294912*8  = 2359296 B
    float4*   tW  = (float4*)(ws + 2359296);        // 294912*16 = 4718592 B
    _Float16* wt2 = (_Float16*)(ws + 7077888);      // 294912*2  =  589824 B
    _Float16* xt  = (_Float16*)(ws + 7667712);      // 16.7M*2   = 33554432 B
                                                    // total 41222144 B

    prep<<<1152 + 1152 + 2048, 256, 0, stream>>>(grid, w, x, tI, tW, wt2, xt);
    sphconv_gemm<<<(4 * HWp) / BM, 512, 0, stream>>>(xt, wt2, bias, tI, tW, out);
}